// Round 5
// baseline (1903.442 us; speedup 1.0000x reference)
//
#include <hip/hip_runtime.h>
#include <cstddef>

#define HID 64
#define TT 64
#define NFEAT 8
#define TOUTC 12
#define SPB 16
#define NBLK 512
#define NTHR 256
#define TC 4
#define NCHUNK 16

typedef float f4 __attribute__((ext_vector_type(4)));
typedef float f2v __attribute__((ext_vector_type(2)));
typedef short s8 __attribute__((ext_vector_type(8)));
typedef unsigned int u32;
typedef unsigned long long u64;

#define MFMA __builtin_amdgcn_mfma_f32_16x16x32_bf16

// ws (ushort elements): pre-split weight planes.
//   whi: layer0 [256][96], layers1-4 [256][128]  -> 155648 ushorts
//   wlo: same structure at +155648
//   bias f32[5][256] at byte 622592
__host__ __device__ constexpr int woff_l(int l) { return (l == 0) ? 0 : 24576 + (l - 1) * 32768; }
#define WLO_BASE 155648
#define BIAS_BYTE 622592

__device__ __forceinline__ float sigm(float x)  { return 1.0f / (1.0f + __expf(-x)); }
__device__ __forceinline__ float tanh_(float x) { return 1.0f - 2.0f / (__expf(2.0f * x) + 1.0f); }

__device__ __forceinline__ void split1(float x, unsigned short& h, unsigned short& l) {
    u32 b = __float_as_uint(x);
    float xh = __uint_as_float(b & 0xFFFF0000u);
    float xl = x - xh;
    h = (unsigned short)(b >> 16);
    l = (unsigned short)(__float_as_uint(xl) >> 16);
}
__device__ __forceinline__ void split8(const float* v, s8& hi, s8& lo) {
#pragma unroll
    for (int j = 0; j < 8; ++j) {
        unsigned short h, l;
        split1(v[j], h, l);
        hi[j] = (short)h;
        lo[j] = (short)l;
    }
}

// ---------------- prologue: pre-split weights into ws ----------------
__global__ __launch_bounds__(256)
void prep_w(const float* __restrict__ Wih0, const float* __restrict__ Whh0,
            const float* __restrict__ bih0, const float* __restrict__ bhh0,
            const float* __restrict__ WihR, const float* __restrict__ WhhR,
            const float* __restrict__ bihR, const float* __restrict__ bhhR,
            unsigned short* __restrict__ ws)
{
    const int gid = blockIdx.x * 256 + threadIdx.x;   // 76*256 = 19456 exactly
    if (gid < 1280) {   // fused biases
        int l = gid >> 8, r = gid & 255;
        float* bws = (float*)((char*)ws + BIAS_BYTE);
        bws[l * 256 + r] = (l == 0) ? (bih0[r] + bhh0[r])
                                    : (bihR[(l - 1) * 256 + r] + bhhR[(l - 1) * 256 + r]);
    }
    int l, row, k0, K;
    if (gid < 3072) { l = 0; row = gid / 12; k0 = (gid % 12) * 8; K = 96; }
    else {
        int g2 = gid - 3072;
        l = 1 + g2 / 4096;
        int r2 = g2 % 4096;
        row = r2 >> 4; k0 = (r2 & 15) * 8; K = 128;
    }
    float v[8];
#pragma unroll
    for (int j = 0; j < 8; ++j) {
        int k = k0 + j;
        float x;
        if (l == 0) {
            if (k < 8)       x = Wih0[row * NFEAT + k];
            else if (k < 32) x = 0.0f;                      // pad x-slice to 32
            else             x = Whh0[row * HID + (k - 32)];
        } else {
            const float* Wi = WihR + (size_t)(l - 1) * 256 * HID;
            const float* Wh = WhhR + (size_t)(l - 1) * 256 * HID;
            x = (k < 64) ? Wi[row * HID + k] : Wh[row * HID + (k - 64)];
        }
        v[j] = x;
    }
    s8 hi, lo;
    split8(v, hi, lo);
    const int eo = woff_l(l) + row * K + k0;
    *(s8*)(ws + eo) = hi;
    *(s8*)(ws + WLO_BASE + eo) = lo;
}

// ---------------- one (layer, 4-step chunk) ----------------
// LDS planes [16][64] bf16, byte = s*128 + elem*2, swizzle ^= (s&7)<<4.
// Buffers [TC][16][64]: + t*2048.
// h ping: even t read hstate write zh; odd t read zh write hstate.
template<int KSX, bool FIRST, bool LAST>
__device__ __forceinline__ void chunk_layer(
    const unsigned short* __restrict__ whi, const unsigned short* __restrict__ wlo,
    const float* __restrict__ wsb,
    const char* xin_hi, const char* xin_lo,
    char* xout_hi, char* xout_lo,
    const float* Xpl,
    char* hst_hi, char* hst_lo, char* zh_hi, char* zh_lo,
    float* hs, f4& c0, int tid, bool lastChunk)
{
    constexpr int NKS = KSX + 2;
    constexpr int K = NKS * 32;
    const int lane = tid & 63;
    const int wv = tid >> 6;
    const int cs = lane & 15;
    const int rq = lane >> 4;
    const int hb = 16 * wv + 4 * rq;
    const int swz = (cs & 7) << 4;

    // weight A-fragments: straight 16B loads of pre-split planes (L2-hit)
    s8 Ah[4][NKS], Al[4][NKS];
#pragma unroll
    for (int a = 0; a < 4; ++a) {
        const int row = 64 * a + 16 * wv + cs;
#pragma unroll
        for (int ks = 0; ks < NKS; ++ks) {
            const int eo = row * K + 32 * ks + 8 * rq;
            Ah[a][ks] = *(const s8*)(whi + eo);
            Al[a][ks] = *(const s8*)(wlo + eo);
        }
    }
    f4 bias[4];
#pragma unroll
    for (int a = 0; a < 4; ++a) bias[a] = *(const f4*)(wsb + 64 * a + hb);

#pragma unroll
    for (int t = 0; t < TC; ++t) {
        // ---- x B-fragments ----
        s8 bxh[KSX], bxl[KSX];
        if constexpr (FIRST) {
            if (rq == 0) {
                const float* p = Xpl + t * 128 + cs * 8;
                f4 x0 = *(const f4*)p, x1 = *(const f4*)(p + 4);
                float v[8];
#pragma unroll
                for (int j = 0; j < 4; ++j) { v[j] = x0[j]; v[4 + j] = x1[j]; }
                split8(v, bxh[0], bxl[0]);
            } else {
                s8 z = {0,0,0,0,0,0,0,0};
                bxh[0] = z; bxl[0] = z;   // A-side is zero for k>=8 anyway
            }
        } else {
#pragma unroll
            for (int ks = 0; ks < KSX; ++ks) {
                const int bo = (t * 2048 + cs * 128 + 64 * ks + 16 * rq) ^ swz;
                bxh[ks] = *(const s8*)(xin_hi + bo);
                bxl[ks] = *(const s8*)(xin_lo + bo);
            }
        }
        // ---- h B-fragments ----
        const char* shi = (t & 1) ? zh_hi : hst_hi;
        const char* slo = (t & 1) ? zh_lo : hst_lo;
        s8 bhh[2], bhl[2];
#pragma unroll
        for (int kk = 0; kk < 2; ++kk) {
            const int ho = (cs * 128 + 64 * kk + 16 * rq) ^ swz;
            bhh[kk] = *(const s8*)(shi + ho);
            bhl[kk] = *(const s8*)(slo + ho);
        }
        // ---- MFMA: two independent chains per gate ----
        f4 c1[4], c2[4];
#pragma unroll
        for (int a = 0; a < 4; ++a) { c1[a] = bias[a]; f4 z = {0,0,0,0}; c2[a] = z; }
#pragma unroll
        for (int a = 0; a < 4; ++a)
#pragma unroll
            for (int ks = 0; ks < KSX; ++ks) {
                c1[a] = MFMA(Ah[a][ks], bxh[ks], c1[a], 0, 0, 0);
                c2[a] = MFMA(Al[a][ks], bxh[ks], c2[a], 0, 0, 0);
                c2[a] = MFMA(Ah[a][ks], bxl[ks], c2[a], 0, 0, 0);
            }
#pragma unroll
        for (int a = 0; a < 4; ++a)
#pragma unroll
            for (int kk = 0; kk < 2; ++kk) {
                c1[a] = MFMA(Ah[a][KSX + kk], bhh[kk], c1[a], 0, 0, 0);
                c2[a] = MFMA(Al[a][KSX + kk], bhh[kk], c2[a], 0, 0, 0);
                c2[a] = MFMA(Ah[a][KSX + kk], bhl[kk], c2[a], 0, 0, 0);
            }
        // ---- activations ----
        float hv[4];
#pragma unroll
        for (int r = 0; r < 4; ++r) {
            float ig = sigm(c1[0][r] + c2[0][r]);
            float fg = sigm(c1[1][r] + c2[1][r]);
            float gg = tanh_(c1[2][r] + c2[2][r]);
            float og = sigm(c1[3][r] + c2[3][r]);
            float cc = fg * c0[r] + ig * gg;
            c0[r] = cc;
            hv[r] = og * tanh_(cc);
        }
        // ---- split + store h (next-step ping + next-layer buffer) ----
        u64 ph = 0, pl = 0;
#pragma unroll
        for (int r = 0; r < 4; ++r) {
            unsigned short uh, ul;
            split1(hv[r], uh, ul);
            ph |= (u64)uh << (16 * r);
            pl |= (u64)ul << (16 * r);
        }
        char* dhi = (t & 1) ? hst_hi : zh_hi;
        char* dlo = (t & 1) ? hst_lo : zh_lo;
        const int wo = (cs * 128 + 32 * wv + 8 * rq) ^ swz;
        *(u64*)(dhi + wo) = ph;
        *(u64*)(dlo + wo) = pl;
        if constexpr (!LAST) {
            const int oo = (t * 2048 + cs * 128 + 32 * wv + 8 * rq) ^ swz;
            *(u64*)(xout_hi + oo) = ph;
            *(u64*)(xout_lo + oo) = pl;
        } else {
            if (lastChunk && t == TC - 1) {
                f4 hvec = {hv[0], hv[1], hv[2], hv[3]};
                *(f4*)(hs + cs * 68 + hb) = hvec;
            }
        }
        __syncthreads();
    }
}

// ---------------- main persistent kernel ----------------
// LDS map (bytes): b0 hi/lo @0/8192, b1 hi/lo @16384/24576,
// hstate[5] (hi+lo 4096 each) @32768, zh hi/lo @53248/55296,
// Xpl f32[4][16][8] @57344, hs f32[16][68] @59392. total 63744.
__global__ __launch_bounds__(NTHR, 2)
void lstm_chunk(const float* __restrict__ Xj,
                const float* __restrict__ Wout, const float* __restrict__ bout,
                float* __restrict__ out, const unsigned short* __restrict__ ws)
{
    __shared__ char sm[63744];
    char* b0_hi = sm;            char* b0_lo = sm + 8192;
    char* b1_hi = sm + 16384;    char* b1_lo = sm + 24576;
    char* hst   = sm + 32768;
    char* zh_hi = sm + 53248;    char* zh_lo = sm + 55296;
    float* Xpl  = (float*)(sm + 57344);
    float* hs   = (float*)(sm + 59392);

    const int tid  = threadIdx.x;
    const int seq0 = blockIdx.x * SPB;

    // zero hstate (5120 u32)
#pragma unroll
    for (int i = 0; i < 20; ++i)
        ((u32*)hst)[tid + 256 * i] = 0u;

    f4 z4 = {0.f, 0.f, 0.f, 0.f};
    f4 cl0 = z4, cl1 = z4, cl2 = z4, cl3 = z4, cl4 = z4;

    const unsigned short* wlo = ws + WLO_BASE;
    const float* bws = (const float*)((const char*)ws + BIAS_BYTE);

#pragma unroll 1
    for (int c = 0; c < NCHUNK; ++c) {
        {   // stage Xj chunk -> Xpl  (tid = s*16 + t*4 + pr)
            int s = tid >> 4, t = (tid >> 2) & 3, pr = tid & 3;
            const float* p = Xj + ((size_t)(seq0 + s) * TT + (c * TC + t)) * NFEAT + 2 * pr;
            f2v v = *(const f2v*)p;
            *(f2v*)(Xpl + t * 128 + s * 8 + 2 * pr) = v;
        }
        __syncthreads();   // Xpl staged; also covers hstate zero-init on c==0
        const bool lc = (c == NCHUNK - 1);

        chunk_layer<1, true,  false>(ws + woff_l(0), wlo + woff_l(0), bws + 0 * 256,
                                     nullptr, nullptr, b0_hi, b0_lo, Xpl,
                                     hst + 0 * 4096, hst + 0 * 4096 + 2048, zh_hi, zh_lo,
                                     hs, cl0, tid, lc);
        chunk_layer<2, false, false>(ws + woff_l(1), wlo + woff_l(1), bws + 1 * 256,
                                     b0_hi, b0_lo, b1_hi, b1_lo, nullptr,
                                     hst + 1 * 4096, hst + 1 * 4096 + 2048, zh_hi, zh_lo,
                                     hs, cl1, tid, lc);
        chunk_layer<2, false, false>(ws + woff_l(2), wlo + woff_l(2), bws + 2 * 256,
                                     b1_hi, b1_lo, b0_hi, b0_lo, nullptr,
                                     hst + 2 * 4096, hst + 2 * 4096 + 2048, zh_hi, zh_lo,
                                     hs, cl2, tid, lc);
        chunk_layer<2, false, false>(ws + woff_l(3), wlo + woff_l(3), bws + 3 * 256,
                                     b0_hi, b0_lo, b1_hi, b1_lo, nullptr,
                                     hst + 3 * 4096, hst + 3 * 4096 + 2048, zh_hi, zh_lo,
                                     hs, cl3, tid, lc);
        chunk_layer<2, false, true >(ws + woff_l(4), wlo + woff_l(4), bws + 4 * 256,
                                     b1_hi, b1_lo, nullptr, nullptr, nullptr,
                                     hst + 4 * 4096, hst + 4 * 4096 + 2048, zh_hi, zh_lo,
                                     hs, cl4, tid, lc);
    }

    __syncthreads();
    // output projection: 16 seqs x 12 outs
    for (int it = tid; it < SPB * TOUTC; it += NTHR) {
        int s = it / TOUTC, o = it % TOUTC;
        float sum = bout[o];
#pragma unroll 8
        for (int j = 0; j < HID; ++j)
            sum = fmaf(Wout[o * HID + j], hs[s * 68 + j], sum);
        out[(size_t)(seq0 + s) * TOUTC + o] = sum;
    }
}

extern "C" void kernel_launch(void* const* d_in, const int* in_sizes, int n_in,
                              void* d_out, int out_size, void* d_ws, size_t ws_size,
                              hipStream_t stream)
{
    const float* Xj   = (const float*)d_in[1];
    const float* Wih0 = (const float*)d_in[3];
    const float* Whh0 = (const float*)d_in[4];
    const float* bih0 = (const float*)d_in[5];
    const float* bhh0 = (const float*)d_in[6];
    const float* WihR = (const float*)d_in[7];
    const float* WhhR = (const float*)d_in[8];
    const float* bihR = (const float*)d_in[9];
    const float* bhhR = (const float*)d_in[10];
    const float* Wout = (const float*)d_in[11];
    const float* bout = (const float*)d_in[12];
    float* out = (float*)d_out;
    unsigned short* ws = (unsigned short*)d_ws;

    prep_w<<<76, 256, 0, stream>>>(Wih0, Whh0, bih0, bhh0, WihR, WhhR, bihR, bhhR, ws);
    lstm_chunk<<<NBLK, NTHR, 0, stream>>>(Xj, Wout, bout, out, ws);
}

// Round 6
// 613.511 us; speedup vs baseline: 3.1025x; 3.1025x over previous
//
#include <hip/hip_runtime.h>
#include <cstddef>

#define HID 64
#define TT 64
#define NFEAT 8
#define TOUTC 12
#define SPB 16
#define NBLK 512
#define NTHR 256

typedef float f4 __attribute__((ext_vector_type(4)));
typedef _Float16 h8 __attribute__((ext_vector_type(8)));
typedef unsigned int u32;
typedef unsigned long long u64;

#define MFMA16 __builtin_amdgcn_mfma_f32_16x16x32_f16

__device__ __forceinline__ float sigm(float x)  { return 1.0f / (1.0f + __expf(-x)); }
__device__ __forceinline__ float tanh_(float x) { return 1.0f - 2.0f / (__expf(2.0f * x) + 1.0f); }

// weight fp32 -> fp16 hi (RN) + fp16 lo (residual)
__device__ __forceinline__ void splitf16(const float* v, h8& hi, h8& lo) {
#pragma unroll
    for (int j = 0; j < 8; ++j) {
        _Float16 h = (_Float16)v[j];
        hi[j] = h;
        lo[j] = (_Float16)(v[j] - (float)h);
    }
}

// raw barrier: order LDS only; do NOT drain vmcnt (ws prefetch stays in flight)
#define RAW_BAR() do {                                          \
    asm volatile("s_waitcnt lgkmcnt(0)" ::: "memory");          \
    __builtin_amdgcn_s_barrier();                               \
    __builtin_amdgcn_sched_barrier(0);                          \
} while (0)

// LDS: zh [2][16][64] fp16 (4096 B, XOR-swizzled byte ^= (cs&7)<<4), hs f32[16][68].
// ws:  fp16 [seq][t][HID]  (67 MB) — inter-layer activations, in-place reuse.
//
// MFMA 16x16x32 f16: M = gate rows (4 tiles i,f,g,o x wave's 16 hidden units),
// N = 16 seqs, K = [x (KSX*32); h (2*32)].
// A frag: row=l&15, k=8*(l>>4)+j. B frag: col=l&15, same k. C/D: col=l&15, row=4*(l>>4)+r.
// 2-product: c1 = Whi*b, c2 = Wlo*b; gate = c1+c2 (+bias fp32).
template<int KSX, bool FIRST, bool LAST>
__device__ __forceinline__ void run_layer(
    const float* __restrict__ Wih, const float* __restrict__ Whh,
    const float* __restrict__ bi,  const float* __restrict__ bh,
    const float* __restrict__ Xj,  unsigned short* __restrict__ ws,
    char* zh, float* hs, int tid, int seq0)
{
    constexpr int NKS = KSX + 2;
    const int lane = tid & 63;
    const int wv   = tid >> 6;
    const int cs   = lane & 15;
    const int rq   = lane >> 4;
    const int hb   = 16 * wv + 4 * rq;
    const int swz  = (cs & 7) << 4;
    const int seq  = seq0 + cs;

    // ---- weight A-fragments (fp16 hi/lo) ----
    h8 Ah[4][NKS], Al[4][NKS];
#pragma unroll
    for (int a = 0; a < 4; ++a) {
        const int row = 64 * a + 16 * wv + cs;
#pragma unroll
        for (int ks = 0; ks < NKS; ++ks) {
            float v[8];
            if (ks < KSX) {
                if (FIRST) {
                    const float* p = Wih + (size_t)row * NFEAT;
#pragma unroll
                    for (int j = 0; j < 8; ++j) v[j] = (rq == 0) ? p[j] : 0.0f;
                } else {
                    const float* p = Wih + (size_t)row * HID + 32 * ks + 8 * rq;
#pragma unroll
                    for (int j = 0; j < 8; ++j) v[j] = p[j];
                }
            } else {
                const float* p = Whh + (size_t)row * HID + 32 * (ks - KSX) + 8 * rq;
#pragma unroll
                for (int j = 0; j < 8; ++j) v[j] = p[j];
            }
            splitf16(v, Ah[a][ks], Al[a][ks]);
        }
    }

    // ---- bias fp32 (C/D layout), vector loads ----
    f4 bias[4];
#pragma unroll
    for (int a = 0; a < 4; ++a)
        bias[a] = *(const f4*)(bi + 64 * a + hb) + *(const f4*)(bh + 64 * a + hb);

    // ---- zero both zh buffers (4096 B = 1024 u32) ----
#pragma unroll
    for (int i = 0; i < 4; ++i)
        ((u32*)zh)[tid * 4 + i] = 0u;

    f4 c0 = {0.f, 0.f, 0.f, 0.f};

    // Full barrier: drains prev-layer ws stores (vmcnt) + zh zero visible.
    __syncthreads();

    // ---- x prefetch regs (depth 1, issued at step start, consumed next step) ----
    f4 xf[2], xfn[2];          // FIRST (fp32 x on rq==0 lanes)
    h8 xc[KSX], xn[KSX];       // recurrent (fp16 from ws)

    auto PREF = [&](int t, f4* fx, h8* hx) {
        if (FIRST) {
            if (rq == 0) {
                const float* p = Xj + ((size_t)seq * TT + t) * NFEAT;
                fx[0] = *(const f4*)p;
                fx[1] = *(const f4*)(p + 4);
            } else {
                f4 z = {0.f, 0.f, 0.f, 0.f};
                fx[0] = z; fx[1] = z;
            }
        } else {
            const unsigned short* p = ws + ((size_t)seq * TT + t) * HID;
#pragma unroll
            for (int ks = 0; ks < KSX; ++ks)
                hx[ks] = *(const h8*)(p + 32 * ks + 8 * rq);
        }
    };

    PREF(0, xf, xc);

    int p = 0;
#pragma unroll 1
    for (int t = 0; t < TT; ++t) {
        if (t + 1 < TT) PREF(t + 1, xfn, xn);   // issue early: full-step latency window

        // ---- x B-fragments (single fp16) ----
        h8 bx[KSX];
        if constexpr (FIRST) {
#pragma unroll
            for (int j = 0; j < 4; ++j) {
                bx[0][j]     = (_Float16)xf[0][j];
                bx[0][4 + j] = (_Float16)xf[1][j];
            }
        } else {
#pragma unroll
            for (int ks = 0; ks < KSX; ++ks) bx[ks] = xc[ks];
        }

        // ---- h B-fragments from LDS (swizzled, single fp16) ----
        h8 bhh[2];
#pragma unroll
        for (int kk = 0; kk < 2; ++kk) {
            const int ho = p * 2048 + ((cs * 128 + 64 * kk + 16 * rq) ^ swz);
            bhh[kk] = *(const h8*)(zh + ho);
        }

        // ---- MFMA: two independent chains (w-hi, w-lo) per gate ----
        f4 c1[4], c2[4];
#pragma unroll
        for (int a = 0; a < 4; ++a) { c1[a] = bias[a]; f4 z = {0,0,0,0}; c2[a] = z; }
#pragma unroll
        for (int a = 0; a < 4; ++a)
#pragma unroll
            for (int ks = 0; ks < KSX; ++ks) {
                c1[a] = MFMA16(Ah[a][ks], bx[ks], c1[a], 0, 0, 0);
                c2[a] = MFMA16(Al[a][ks], bx[ks], c2[a], 0, 0, 0);
            }
#pragma unroll
        for (int a = 0; a < 4; ++a)
#pragma unroll
            for (int kk = 0; kk < 2; ++kk) {
                c1[a] = MFMA16(Ah[a][KSX + kk], bhh[kk], c1[a], 0, 0, 0);
                c2[a] = MFMA16(Al[a][KSX + kk], bhh[kk], c2[a], 0, 0, 0);
            }

        // ---- activations + cell update ----
        float hv[4];
#pragma unroll
        for (int r = 0; r < 4; ++r) {
            float ig = sigm(c1[0][r] + c2[0][r]);
            float fg = sigm(c1[1][r] + c2[1][r]);
            float gg = tanh_(c1[2][r] + c2[2][r]);
            float og = sigm(c1[3][r] + c2[3][r]);
            float cc = fg * c0[r] + ig * gg;
            c0[r] = cc;
            hv[r] = og * tanh_(cc);
        }

        // ---- pack h to fp16 (RN) once; write LDS ping + ws ----
        u64 ph = 0;
#pragma unroll
        for (int r = 0; r < 4; ++r) {
            _Float16 hh = (_Float16)hv[r];
            ph |= (u64)(*(unsigned short*)&hh) << (16 * r);
        }
        {
            const int wo = (1 ^ p) * 2048 + ((cs * 128 + 2 * hb) ^ swz);
            *(u64*)(zh + wo) = ph;
        }
        if constexpr (!LAST) {
            *(u64*)(ws + ((size_t)seq * TT + t) * HID + hb) = ph;
        } else {
            if (t == TT - 1) {
                f4 hvec = {hv[0], hv[1], hv[2], hv[3]};
                *(f4*)(hs + cs * 68 + hb) = hvec;
            }
        }

        // rotate prefetch regs
        if (t + 1 < TT) {
            if constexpr (FIRST) { xf[0] = xfn[0]; xf[1] = xfn[1]; }
            else {
#pragma unroll
                for (int ks = 0; ks < KSX; ++ks) xc[ks] = xn[ks];
            }
        }

        RAW_BAR();   // LDS-only ordering; ws prefetch/stores stay in flight
        p ^= 1;
    }
}

__global__ __launch_bounds__(NTHR, 2)
void lstm_mfma16(const float* __restrict__ Xj,
                 const float* __restrict__ Wih0, const float* __restrict__ Whh0,
                 const float* __restrict__ bih0, const float* __restrict__ bhh0,
                 const float* __restrict__ WihR, const float* __restrict__ WhhR,
                 const float* __restrict__ bihR, const float* __restrict__ bhhR,
                 const float* __restrict__ Wout, const float* __restrict__ bout,
                 float* __restrict__ out, unsigned short* __restrict__ ws)
{
    __shared__ char smraw[8448];
    char*  zh = smraw;                    // [2][16][64] fp16
    float* hs = (float*)(smraw + 4096);   // [16][68] f32

    const int tid  = threadIdx.x;
    const int seq0 = blockIdx.x * SPB;

    run_layer<1, true,  false>(Wih0, Whh0, bih0, bhh0, Xj, ws, zh, hs, tid, seq0);
#pragma unroll 1
    for (int l = 0; l < 3; ++l)
        run_layer<2, false, false>(WihR + (size_t)l * 256 * HID, WhhR + (size_t)l * 256 * HID,
                                   bihR + (size_t)l * 256, bhhR + (size_t)l * 256,
                                   nullptr, ws, zh, hs, tid, seq0);
    run_layer<2, false, true >(WihR + (size_t)3 * 256 * HID, WhhR + (size_t)3 * 256 * HID,
                               bihR + (size_t)3 * 256, bhhR + (size_t)3 * 256,
                               nullptr, ws, zh, hs, tid, seq0);

    __syncthreads();   // hs visible (lgkm+barrier; full sync is fine here)
    // ---- output projection: 16 seqs x 12 outs ----
    for (int it = tid; it < SPB * TOUTC; it += NTHR) {
        int s = it / TOUTC, o = it % TOUTC;
        float sum = bout[o];
#pragma unroll 8
        for (int j = 0; j < HID; ++j)
            sum = fmaf(Wout[o * HID + j], hs[s * 68 + j], sum);
        out[(size_t)(seq0 + s) * TOUTC + o] = sum;
    }
}

extern "C" void kernel_launch(void* const* d_in, const int* in_sizes, int n_in,
                              void* d_out, int out_size, void* d_ws, size_t ws_size,
                              hipStream_t stream)
{
    const float* Xj   = (const float*)d_in[1];
    const float* Wih0 = (const float*)d_in[3];
    const float* Whh0 = (const float*)d_in[4];
    const float* bih0 = (const float*)d_in[5];
    const float* bhh0 = (const float*)d_in[6];
    const float* WihR = (const float*)d_in[7];
    const float* WhhR = (const float*)d_in[8];
    const float* bihR = (const float*)d_in[9];
    const float* bhhR = (const float*)d_in[10];
    const float* Wout = (const float*)d_in[11];
    const float* bout = (const float*)d_in[12];
    float* out = (float*)d_out;

    lstm_mfma16<<<NBLK, NTHR, 0, stream>>>(Xj, Wih0, Whh0, bih0, bhh0,
                                           WihR, WhhR, bihR, bhhR,
                                           Wout, bout, out, (unsigned short*)d_ws);
}